// Round 2
// baseline (391.922 us; speedup 1.0000x reference)
//
#include <hip/hip_runtime.h>
#include <hip/hip_bf16.h>

typedef unsigned short u16;
typedef short bf16x8 __attribute__((ext_vector_type(8)));   // 8 bf16 (4 VGPR)
typedef float f32x4 __attribute__((ext_vector_type(4)));
typedef unsigned short u16x8 __attribute__((ext_vector_type(8)));

#define NTOT 128
#define CIN 256
#define HW 784
#define PLANE 200704  // 256*784

// ws layout (bytes)
#define OFF_PPART 0         // 14*128*256 f32 = 1,835,008
#define OFF_PS    1835008   // 128*256 f32   =   131,072
#define OFF_GATE  1966080   // 128*256 f32   =   131,072
#define OFF_WT    2097152   // 9*8*256*32 bf16 = 1,179,648
#define OFF_XST   3276800   // 128*784*256 bf16 = 51,380,224

__device__ __forceinline__ u16 f2b(float f) {
    union { float f; unsigned u; } v; v.f = f;
    unsigned r = v.u + 0x7FFF + ((v.u >> 16) & 1);   // RNE
    return (u16)(r >> 16);
}
__device__ __forceinline__ float b2f(u16 u) {
    union { unsigned u; float f; } v; v.u = ((unsigned)u) << 16;
    return v.f;
}

// ---------------- k0: weight transform net_w[co][ci][ky][kx] f32 -> Wt[tap][cb][co][cl] bf16
__global__ __launch_bounds__(256) void k_wt(const float* __restrict__ netw, u16* __restrict__ wt) {
    int id = blockIdx.x * 256 + threadIdx.x;            // 0..589823
    int cl = id & 31, co = (id >> 5) & 255, cb = (id >> 13) & 7, tap = id >> 16;
    int ci = cb * 32 + cl;
    wt[id] = f2b(netw[((size_t)co * 256 + ci) * 9 + tap]);
}

// ---------------- k1: temporal shift + pool partials + transpose to xst[nt][pix][c] bf16
__global__ __launch_bounds__(256) void k_shift(const float* __restrict__ x,
                                               const float* __restrict__ taw,
                                               float* __restrict__ ppart,
                                               u16* __restrict__ xst) {
    const int pt = blockIdx.x;      // 0..13 (56-pixel tiles)
    const int nt = blockIdx.y;      // 0..127
    const int tid = threadIdx.x, wv = tid >> 6, ln = tid & 63;
    const int p0 = pt * 56;
    const int tseg = nt & 7;
    __shared__ float taw_l[768];
    __shared__ __align__(16) u16 xs_l[256 * 57];
    for (int i = tid; i < 768; i += 256) taw_l[i] = taw[i];
    __syncthreads();
    const int p = ln;
    const bool act = p < 56;
    for (int j = 0; j < 64; ++j) {
        const int c = j * 4 + wv;
        const int base = c * HW + p0 + p;
        float vm = 0.f, v0 = 0.f, vp = 0.f;
        if (act) {
            v0 = x[(size_t)nt * PLANE + base];
            if (tseg > 0) vm = x[(size_t)(nt - 1) * PLANE + base];
            if (tseg < 7) vp = x[(size_t)(nt + 1) * PLANE + base];
        }
        float xs = taw_l[c * 3] * vm + taw_l[c * 3 + 1] * v0 + taw_l[c * 3 + 2] * vp;
        float s = act ? xs : 0.f;
        #pragma unroll
        for (int o = 32; o; o >>= 1) s += __shfl_xor(s, o);
        if (ln == 0) ppart[((size_t)pt * 128 + nt) * 256 + c] = s;
        if (act) xs_l[c * 57 + p] = f2b(xs);
    }
    __syncthreads();
    // transpose-out: 56 pixels x 256 ch, 16B chunks, coalesced
    for (int k = 0; k < 7; ++k) {
        int id = k * 256 + tid;        // 0..1791
        int pp = id >> 5;              // 0..55
        int c0 = (id & 31) * 8;
        u16x8 v;
        #pragma unroll
        for (int i = 0; i < 8; ++i) v[i] = xs_l[(c0 + i) * 57 + pp];
        *(u16x8*)(xst + ((size_t)nt * HW + p0 + pp) * 256 + c0) = v;
    }
}

// ---------------- k2a: reduce pool partials -> ps[nt][c]  (pool of x_shift; NO extra shift:
// ppart already holds partial sums of the SHIFTED values)
__global__ __launch_bounds__(256) void k_pool(const float* __restrict__ ppart,
                                              float* __restrict__ ps) {
    int b = blockIdx.x, c = threadIdx.x;
    for (int t = 0; t < 8; ++t) {
        float s = 0.f;
        for (int q = 0; q < 14; ++q) s += ppart[((size_t)q * 128 + b * 8 + t) * 256 + c];
        ps[(b * 8 + t) * 256 + c] = s * (1.f / 784.f);
    }
}

// ---------------- k2b: SE chain (conv1d over T view + BN(batch stats) + relu + 1x1 + sigmoid)
__global__ __launch_bounds__(256) void k_se(const float* __restrict__ ps,
                                            const float* __restrict__ wse,
                                            const float* __restrict__ gamma,
                                            const float* __restrict__ beta,
                                            const float* __restrict__ w1,
                                            float* __restrict__ gate) {
    __shared__ float y3_l[2048];
    __shared__ float sc_l[16], bi_l[16];
    const int tid = threadIdx.x;
    const int b = tid >> 4, o = tid & 15;    // thread = (batch, out-channel)
    float acc[8] = {0, 0, 0, 0, 0, 0, 0, 0};
    const float* psb = ps + b * 2048;        // row-major [NT,C] viewed flat as [B][C][T]
    for (int c2 = 0; c2 < 256; ++c2) {
        float pv[8];
        #pragma unroll
        for (int i = 0; i < 8; ++i) pv[i] = psb[c2 * 8 + i];
        float ww0 = wse[(o * 256 + c2) * 3];
        float ww1 = wse[(o * 256 + c2) * 3 + 1];
        float ww2 = wse[(o * 256 + c2) * 3 + 2];
        #pragma unroll
        for (int t = 0; t < 8; ++t) {
            float v = ww1 * pv[t];
            if (t > 0) v += ww0 * pv[t - 1];
            if (t < 7) v += ww2 * pv[t + 1];
            acc[t] += v;
        }
    }
    #pragma unroll
    for (int t = 0; t < 8; ++t) y3_l[b * 128 + o * 8 + t] = acc[t];
    __syncthreads();
    if (tid < 16) {
        float s = 0.f, sq = 0.f;
        for (int i = 0; i < 128; ++i) {
            float v = y3_l[(i >> 3) * 128 + tid * 8 + (i & 7)];
            s += v; sq += v * v;
        }
        float m = s * (1.f / 128.f);
        float var = sq * (1.f / 128.f) - m * m;
        float rs = rsqrtf(var + 1e-5f) * gamma[tid];
        sc_l[tid] = rs;
        bi_l[tid] = beta[tid] - m * rs;
    }
    __syncthreads();
    #pragma unroll
    for (int t = 0; t < 8; ++t)
        y3_l[b * 128 + o * 8 + t] = fmaxf(acc[t] * sc_l[o] + bi_l[o], 0.f);
    __syncthreads();
    for (int k = 0; k < 128; ++k) {
        int id = tid + 256 * k;            // 0..32767, flat [B][256][T] == flat [NT][C]
        int bb = id >> 11, o2 = (id >> 3) & 255, t = id & 7;
        float a = 0.f;
        #pragma unroll
        for (int oo = 0; oo < 16; ++oo) a += w1[o2 * 16 + oo] * y3_l[bb * 128 + oo * 8 + t];
        gate[id] = 1.f / (1.f + __expf(-a));
    }
}

// ---------------- k3: 3x3 conv as implicit GEMM, bf16 MFMA, gate fused at staging
__global__ __launch_bounds__(256) void k_conv(const u16* __restrict__ xst,
                                              const float* __restrict__ gate,
                                              const u16* __restrict__ wt,
                                              const float* __restrict__ netb,
                                              float* __restrict__ out) {
    const int pt = blockIdx.x;     // 0..6  : 4-row pixel tile (112 px)
    const int mt = blockIdx.y;     // 0..1  : 128 c_out half
    const int nt = blockIdx.z;     // 0..127
    const int tid = threadIdx.x, wv = tid >> 6, ln = tid & 63;
    __shared__ float gl[256];
    __shared__ __align__(16) u16 a_l[128 * 40];   // [co 128][k 32 pad40]
    __shared__ __align__(16) u16 z_l[180 * 40];   // [pos 6*30][ch 32 pad40]
    gl[tid] = 1.f + gate[nt * 256 + tid];

    int rl[7], cl[7];
    #pragma unroll
    for (int nf = 0; nf < 7; ++nf) {
        int n = nf * 16 + (ln & 15);
        rl[nf] = n / 28; cl[nf] = n % 28;
    }
    const int g8 = (ln >> 4) * 8;
    f32x4 acc[2][7];
    #pragma unroll
    for (int a = 0; a < 2; ++a)
        #pragma unroll
        for (int b = 0; b < 7; ++b) acc[a][b] = (f32x4){0.f, 0.f, 0.f, 0.f};
    const int r0 = pt * 4;

    for (int cb = 0; cb < 8; ++cb) {
        __syncthreads();   // prior readers of z_l done
        // stage halo'd z tile: 6 rows x 30 cols x 32 ch, gate applied, zero-padded
        for (int it = 0; it < 3; ++it) {
            int slot = it * 256 + tid;
            if (slot < 720) {
                int pos = slot >> 2, q = slot & 3;
                int rr = pos / 30, cc = pos % 30;
                int rg = r0 - 1 + rr, cg = cc - 1;
                u16x8 v = (u16x8){0, 0, 0, 0, 0, 0, 0, 0};
                if (rg >= 0 && rg < 28 && cg >= 0 && cg < 28) {
                    u16x8 s = *(const u16x8*)(xst + ((size_t)nt * HW + rg * 28 + cg) * 256 + cb * 32 + q * 8);
                    #pragma unroll
                    for (int i = 0; i < 8; ++i) v[i] = f2b(b2f(s[i]) * gl[cb * 32 + q * 8 + i]);
                }
                *(u16x8*)&z_l[pos * 40 + q * 8] = v;
            }
        }
        for (int tap = 0; tap < 9; ++tap) {
            __syncthreads();   // prior A readers done (also fences z_l ready at tap 0)
            {   // stage A tile 128x32 bf16 (contiguous 8KB in Wt)
                const u16* as = wt + (size_t)tap * 65536 + cb * 8192 + mt * 4096;
                int row = tid >> 1, sg = tid & 1;
                u16x8 v0 = *(const u16x8*)(as + row * 32 + sg * 16);
                u16x8 v1 = *(const u16x8*)(as + row * 32 + sg * 16 + 8);
                *(u16x8*)&a_l[row * 40 + sg * 16] = v0;
                *(u16x8*)&a_l[row * 40 + sg * 16 + 8] = v1;
            }
            __syncthreads();   // A ready
            const int ky = tap / 3, kx = tap % 3;
            bf16x8 af[2];
            #pragma unroll
            for (int mf = 0; mf < 2; ++mf)
                af[mf] = *(const bf16x8*)&a_l[(wv * 32 + mf * 16 + (ln & 15)) * 40 + g8];
            #pragma unroll
            for (int nf = 0; nf < 7; ++nf) {
                int pos = (rl[nf] + ky) * 30 + cl[nf] + kx;
                bf16x8 bf = *(const bf16x8*)&z_l[pos * 40 + g8];
                acc[0][nf] = __builtin_amdgcn_mfma_f32_16x16x32_bf16(af[0], bf, acc[0][nf], 0, 0, 0);
                acc[1][nf] = __builtin_amdgcn_mfma_f32_16x16x32_bf16(af[1], bf, acc[1][nf], 0, 0, 0);
            }
        }
    }
    // epilogue: D lane layout col = lane&15, row = (lane>>4)*4 + i
    const int colp = ln & 15, rowp = (ln >> 4) * 4;
    const int p0 = pt * 112;
    #pragma unroll
    for (int mf = 0; mf < 2; ++mf) {
        #pragma unroll
        for (int i = 0; i < 4; ++i) {
            int co = mt * 128 + wv * 32 + mf * 16 + rowp + i;
            float bias = netb[co];
            float* ob = out + ((size_t)nt * 256 + co) * HW + p0;
            #pragma unroll
            for (int nf = 0; nf < 7; ++nf)
                ob[nf * 16 + colp] = acc[mf][nf][i] + bias;
        }
    }
}

extern "C" void kernel_launch(void* const* d_in, const int* in_sizes, int n_in,
                              void* d_out, int out_size, void* d_ws, size_t ws_size,
                              hipStream_t stream) {
    const float* x     = (const float*)d_in[0];
    const float* taw   = (const float*)d_in[1];
    const float* wse   = (const float*)d_in[2];
    const float* gamma = (const float*)d_in[3];
    const float* beta  = (const float*)d_in[4];
    const float* w1    = (const float*)d_in[5];
    const float* netw  = (const float*)d_in[6];
    const float* netb  = (const float*)d_in[7];
    float* out = (float*)d_out;
    char* ws = (char*)d_ws;
    float* ppart = (float*)(ws + OFF_PPART);
    float* ps    = (float*)(ws + OFF_PS);
    float* gate  = (float*)(ws + OFF_GATE);
    u16*   wt    = (u16*)(ws + OFF_WT);
    u16*   xst   = (u16*)(ws + OFF_XST);

    k_wt<<<dim3(2304), dim3(256), 0, stream>>>(netw, wt);
    k_shift<<<dim3(14, 128), dim3(256), 0, stream>>>(x, taw, ppart, xst);
    k_pool<<<dim3(16), dim3(256), 0, stream>>>(ppart, ps);
    k_se<<<dim3(1), dim3(256), 0, stream>>>(ps, wse, gamma, beta, w1, gate);
    k_conv<<<dim3(7, 2, 128), dim3(256), 0, stream>>>(xst, gate, wt, netb, out);
}

// Round 3
// 316.565 us; speedup vs baseline: 1.2380x; 1.2380x over previous
//
#include <hip/hip_runtime.h>
#include <hip/hip_bf16.h>

typedef unsigned short u16;
typedef short bf16x8 __attribute__((ext_vector_type(8)));
typedef float f32x4 __attribute__((ext_vector_type(4)));
typedef unsigned short u16x8 __attribute__((ext_vector_type(8)));

#define HW 784
#define PLANE 200704      // 256*784
#define PADPX 900         // 30*30 padded image

// ws layout (bytes)
#define OFF_PX   0          // 128*256 f32
#define OFF_PS   131072     // 128*256 f32
#define OFF_GL   262144     // 128*256 f32 (1+sigmoid)
#define OFF_WT   393216     // 9*8*256*32 bf16 = 1,179,648
#define OFF_XSTG 1572864    // 128*900*256 bf16 = 58,982,400 (+32KB slack)

__device__ __forceinline__ u16 f2b(float f) {
    union { float f; unsigned u; } v; v.f = f;
    unsigned r = v.u + 0x7FFF + ((v.u >> 16) & 1);   // RNE
    return (u16)(r >> 16);
}

typedef __attribute__((address_space(1))) const unsigned int gas_u32;
typedef __attribute__((address_space(3))) unsigned int las_u32;
__device__ __forceinline__ void gload16(const void* g, void* l) {
    __builtin_amdgcn_global_load_lds((gas_u32*)g, (las_u32*)l, 16, 0, 0);
}

// ---------------- k_wt: net_w[co][ci][3][3] f32 -> wt[tap][cb][co][cl32] bf16
__global__ __launch_bounds__(256) void k_wt(const float* __restrict__ netw, u16* __restrict__ wt) {
    int id = blockIdx.x * 256 + threadIdx.x;
    int cl = id & 31, co = (id >> 5) & 255, cb = (id >> 13) & 7, tap = id >> 16;
    int ci = cb * 32 + cl;
    wt[id] = f2b(netw[((size_t)co * 256 + ci) * 9 + tap]);
}

// ---------------- k_pool0: spatial mean of x -> px[nt][c]
__global__ __launch_bounds__(256) void k_pool0(const float* __restrict__ x, float* __restrict__ px) {
    const int nt = blockIdx.x, cg = blockIdx.y;
    const int wv = threadIdx.x >> 6, ln = threadIdx.x & 63;
    for (int i = 0; i < 16; ++i) {
        int c = cg * 64 + wv * 16 + i;
        const float4* xp = (const float4*)(x + (size_t)nt * PLANE + (size_t)c * HW);
        float s = 0.f;
        for (int k = ln; k < 196; k += 64) { float4 v = xp[k]; s += v.x + v.y + v.z + v.w; }
        #pragma unroll
        for (int o = 32; o; o >>= 1) s += __shfl_xor(s, o);
        if (ln == 0) px[nt * 256 + c] = s * (1.f / 784.f);
    }
}

// ---------------- k_zero: zero the 116 border pixels of each padded image
__global__ __launch_bounds__(256) void k_zero(u16* __restrict__ xstg) {
    const int nt = blockIdx.x, tid = threadIdx.x;
    for (int it = 0; it < 15; ++it) {
        int cid = it * 256 + tid;
        if (cid < 3712) {
            int pxi = cid >> 5, ch = cid & 31;
            int pidx;
            if (pxi < 30) pidx = pxi;
            else if (pxi < 60) pidx = 29 * 30 + (pxi - 30);
            else { int k = pxi - 60; pidx = (1 + (k >> 1)) * 30 + (k & 1) * 29; }
            *(u16x8*)(xstg + ((size_t)nt * PADPX + pidx) * 256 + ch * 8) = (u16x8){0,0,0,0,0,0,0,0};
        }
    }
}

// ---------------- k_se0: temporal 3-tap shift of pooled values (shift∘pool == pool∘shift)
__global__ __launch_bounds__(256) void k_se0(const float* __restrict__ px,
                                             const float* __restrict__ taw,
                                             float* __restrict__ ps) {
    int b = blockIdx.x, c = threadIdx.x;
    float w0 = taw[c * 3], w1 = taw[c * 3 + 1], w2 = taw[c * 3 + 2];
    float pr[8];
    #pragma unroll
    for (int t = 0; t < 8; ++t) pr[t] = px[(b * 8 + t) * 256 + c];
    #pragma unroll
    for (int t = 0; t < 8; ++t) {
        float v = w1 * pr[t];
        if (t > 0) v += w0 * pr[t - 1];
        if (t < 7) v += w2 * pr[t + 1];
        ps[(b * 8 + t) * 256 + c] = v;
    }
}

// ---------------- k_se: SE chain -> gl = 1 + sigmoid
__global__ __launch_bounds__(256) void k_se(const float* __restrict__ ps,
                                            const float* __restrict__ wse,
                                            const float* __restrict__ gamma,
                                            const float* __restrict__ beta,
                                            const float* __restrict__ w1,
                                            float* __restrict__ gl) {
    __shared__ float y3_l[2048];
    __shared__ float sc_l[16], bi_l[16];
    const int tid = threadIdx.x;
    const int b = tid >> 4, o = tid & 15;
    float acc[8] = {0, 0, 0, 0, 0, 0, 0, 0};
    const float* psb = ps + b * 2048;        // row-major [NT,C] viewed flat as [B][C][T]
    for (int c2 = 0; c2 < 256; ++c2) {
        float pv[8];
        #pragma unroll
        for (int i = 0; i < 8; ++i) pv[i] = psb[c2 * 8 + i];
        float ww0 = wse[(o * 256 + c2) * 3];
        float ww1 = wse[(o * 256 + c2) * 3 + 1];
        float ww2 = wse[(o * 256 + c2) * 3 + 2];
        #pragma unroll
        for (int t = 0; t < 8; ++t) {
            float v = ww1 * pv[t];
            if (t > 0) v += ww0 * pv[t - 1];
            if (t < 7) v += ww2 * pv[t + 1];
            acc[t] += v;
        }
    }
    #pragma unroll
    for (int t = 0; t < 8; ++t) y3_l[b * 128 + o * 8 + t] = acc[t];
    __syncthreads();
    if (tid < 16) {
        float s = 0.f, sq = 0.f;
        for (int i = 0; i < 128; ++i) {
            float v = y3_l[(i >> 3) * 128 + tid * 8 + (i & 7)];
            s += v; sq += v * v;
        }
        float m = s * (1.f / 128.f);
        float var = sq * (1.f / 128.f) - m * m;
        float rs = rsqrtf(var + 1e-5f) * gamma[tid];
        sc_l[tid] = rs;
        bi_l[tid] = beta[tid] - m * rs;
    }
    __syncthreads();
    #pragma unroll
    for (int t = 0; t < 8; ++t)
        y3_l[b * 128 + o * 8 + t] = fmaxf(acc[t] * sc_l[o] + bi_l[o], 0.f);
    __syncthreads();
    for (int k = 0; k < 128; ++k) {
        int id = tid + 256 * k;            // flat [B][256][T] == flat [NT][C]
        int bb = id >> 11, o2 = (id >> 3) & 255, t = id & 7;
        float a = 0.f;
        #pragma unroll
        for (int oo = 0; oo < 16; ++oo) a += w1[o2 * 16 + oo] * y3_l[bb * 128 + oo * 8 + t];
        gl[id] = 1.f + 1.f / (1.f + __expf(-a));
    }
}

// ---------------- k_fused: temporal shift + gate + transpose -> xstg[nt][padpix][c] bf16
__global__ __launch_bounds__(256) void k_fused(const float* __restrict__ x,
                                               const float* __restrict__ taw,
                                               const float* __restrict__ gl,
                                               u16* __restrict__ xstg) {
    const int pt = blockIdx.x;      // 0..13 (56-pixel strips = 2 rows)
    const int nt = blockIdx.y;
    const int tid = threadIdx.x, wv = tid >> 6, ln = tid & 63;
    const int p0 = pt * 56;
    const int tseg = nt & 7;
    __shared__ float taw_l[768];
    __shared__ float gl_l[256];
    __shared__ __align__(16) u16 xs_l[256 * 57];
    for (int i = tid; i < 768; i += 256) taw_l[i] = taw[i];
    gl_l[tid] = gl[nt * 256 + tid];
    __syncthreads();
    const int p = ln;
    const bool act = p < 56;
    for (int j = 0; j < 64; ++j) {
        const int c = j * 4 + wv;
        const int base = c * HW + p0 + p;
        float vm = 0.f, v0 = 0.f, vp = 0.f;
        if (act) {
            v0 = x[(size_t)nt * PLANE + base];
            if (tseg > 0) vm = x[(size_t)(nt - 1) * PLANE + base];
            if (tseg < 7) vp = x[(size_t)(nt + 1) * PLANE + base];
        }
        float xs = (taw_l[c * 3] * vm + taw_l[c * 3 + 1] * v0 + taw_l[c * 3 + 2] * vp) * gl_l[c];
        if (act) xs_l[c * 57 + p] = f2b(xs);
    }
    __syncthreads();
    for (int k = 0; k < 7; ++k) {
        int id = k * 256 + tid;        // 0..1791
        int pp = id >> 5;              // 0..55
        int c0 = (id & 31) * 8;
        u16x8 v;
        #pragma unroll
        for (int i = 0; i < 8; ++i) v[i] = xs_l[(c0 + i) * 57 + pp];
        int gp = p0 + pp;
        int r = gp / 28, cc = gp % 28;
        int pidx = (r + 1) * 30 + (cc + 1);
        *(u16x8*)(xstg + ((size_t)nt * PADPX + pidx) * 256 + c0) = v;
    }
}

// ---------------- k_conv: 3x3 conv, full-256-co blocks, reg-A, async-LDS z, dbuf
__global__ __launch_bounds__(256, 2) void k_conv(const u16* __restrict__ xstg,
                                                 const u16* __restrict__ wt,
                                                 const float* __restrict__ netb,
                                                 float* __restrict__ out) {
    const int pt = blockIdx.x;   // 0..6 : 4 output rows (112 px)
    const int nt = blockIdx.y;   // 0..127
    const int tid = threadIdx.x, wv = tid >> 6, ln = tid & 63;
    __shared__ __align__(16) u16 z_l[2][6144];   // [pix 192][ch 32], 12KB each
    const int g8 = (ln >> 4) * 8;
    const int p = ln & 15;
    int pb[7];
    #pragma unroll
    for (int nf = 0; nf < 7; ++nf) {
        int n = nf * 16 + p;
        pb[nf] = (n / 28) * 30 + (n % 28);     // padded base pos (before +ky*30+kx)
    }
    f32x4 acc[4][7];
    #pragma unroll
    for (int a = 0; a < 4; ++a)
        #pragma unroll
        for (int b = 0; b < 7; ++b) acc[a][b] = (f32x4){0.f, 0.f, 0.f, 0.f};

    const size_t gbase = ((size_t)nt * PADPX + pt * 120) * 256;   // u16 units

    // stage one cb-slice (180 px x 32 ch) via 12 wave-uniform 1KB async copies
    auto stage = [&](int cb, int buf) {
        #pragma unroll
        for (int s = 0; s < 3; ++s) {
            int k = wv * 3 + s;
            int chunk = k * 64 + ln;
            int pix = chunk >> 2, q = chunk & 3;
            const u16* g = xstg + gbase + (size_t)pix * 256 + cb * 32 + q * 8;
            gload16(g, &z_l[buf][k * 512]);
        }
    };

    stage(0, 0);
    for (int cb = 0; cb < 8; ++cb) {
        __syncthreads();                       // vmcnt(0) before barrier: buf[cb&1] ready
        if (cb < 7) stage(cb + 1, (cb + 1) & 1);
        const u16* zl = z_l[cb & 1];
        #pragma unroll
        for (int tap = 0; tap < 9; ++tap) {
            const u16* ab = wt + (((size_t)tap * 8 + cb) * 256 + wv * 64) * 32;
            bf16x8 af[4];
            #pragma unroll
            for (int mf = 0; mf < 4; ++mf)
                af[mf] = *(const bf16x8*)(ab + (mf * 16 + p) * 32 + g8);
            const int po = (tap / 3) * 30 + (tap % 3);
            #pragma unroll
            for (int nf = 0; nf < 7; ++nf) {
                bf16x8 bf = *(const bf16x8*)&zl[(pb[nf] + po) * 32 + g8];
                acc[0][nf] = __builtin_amdgcn_mfma_f32_16x16x32_bf16(af[0], bf, acc[0][nf], 0, 0, 0);
                acc[1][nf] = __builtin_amdgcn_mfma_f32_16x16x32_bf16(af[1], bf, acc[1][nf], 0, 0, 0);
                acc[2][nf] = __builtin_amdgcn_mfma_f32_16x16x32_bf16(af[2], bf, acc[2][nf], 0, 0, 0);
                acc[3][nf] = __builtin_amdgcn_mfma_f32_16x16x32_bf16(af[3], bf, acc[3][nf], 0, 0, 0);
            }
        }
    }
    // epilogue: D layout col=lane&15, row=(lane>>4)*4+i
    const int colp = ln & 15, rowp = (ln >> 4) * 4;
    const int o0 = pt * 112;
    #pragma unroll
    for (int mf = 0; mf < 4; ++mf) {
        #pragma unroll
        for (int i = 0; i < 4; ++i) {
            int co = wv * 64 + mf * 16 + rowp + i;
            float bias = netb[co];
            float* ob = out + ((size_t)nt * 256 + co) * HW + o0;
            #pragma unroll
            for (int nf = 0; nf < 7; ++nf)
                ob[nf * 16 + colp] = acc[mf][nf][i] + bias;
        }
    }
}

extern "C" void kernel_launch(void* const* d_in, const int* in_sizes, int n_in,
                              void* d_out, int out_size, void* d_ws, size_t ws_size,
                              hipStream_t stream) {
    const float* x     = (const float*)d_in[0];
    const float* taw   = (const float*)d_in[1];
    const float* wse   = (const float*)d_in[2];
    const float* gamma = (const float*)d_in[3];
    const float* beta  = (const float*)d_in[4];
    const float* w1    = (const float*)d_in[5];
    const float* netw  = (const float*)d_in[6];
    const float* netb  = (const float*)d_in[7];
    float* out = (float*)d_out;
    char* ws = (char*)d_ws;
    float* px   = (float*)(ws + OFF_PX);
    float* ps   = (float*)(ws + OFF_PS);
    float* gl   = (float*)(ws + OFF_GL);
    u16*   wt   = (u16*)(ws + OFF_WT);
    u16*   xstg = (u16*)(ws + OFF_XSTG);

    k_wt<<<dim3(2304), dim3(256), 0, stream>>>(netw, wt);
    k_pool0<<<dim3(128, 4), dim3(256), 0, stream>>>(x, px);
    k_zero<<<dim3(128), dim3(256), 0, stream>>>(xstg);
    k_se0<<<dim3(16), dim3(256), 0, stream>>>(px, taw, ps);
    k_se<<<dim3(1), dim3(256), 0, stream>>>(ps, wse, gamma, beta, w1, gl);
    k_fused<<<dim3(14, 128), dim3(256), 0, stream>>>(x, taw, gl, xstg);
    k_conv<<<dim3(7, 128), dim3(256), 0, stream>>>(xstg, wt, netb, out);
}

// Round 4
// 284.265 us; speedup vs baseline: 1.3787x; 1.1136x over previous
//
#include <hip/hip_runtime.h>
#include <hip/hip_bf16.h>

typedef unsigned short u16;
typedef short bf16x8 __attribute__((ext_vector_type(8)));
typedef float f32x4 __attribute__((ext_vector_type(4)));
typedef unsigned short u16x8 __attribute__((ext_vector_type(8)));

#define HW 784
#define PLANE 200704      // 256*784
#define PADPX 900         // 30*30 padded image

// ws layout (bytes)
#define OFF_PX   0          // 128*256 f32
#define OFF_PS   131072     // 128*256 f32
#define OFF_GL   262144     // 128*256 f32 (1+sigmoid)
#define OFF_WT   393216     // 9*8*256*32 bf16 = 1,179,648
#define OFF_XSTG 1572864    // 128*900*256 bf16 = 58,982,400 (+slack)

__device__ __forceinline__ u16 f2b(float f) {
    union { float f; unsigned u; } v; v.f = f;
    unsigned r = v.u + 0x7FFF + ((v.u >> 16) & 1);   // RNE
    return (u16)(r >> 16);
}

typedef __attribute__((address_space(1))) const unsigned int gas_u32;
typedef __attribute__((address_space(3))) unsigned int las_u32;
__device__ __forceinline__ void gload16(const void* g, void* l) {
    __builtin_amdgcn_global_load_lds((gas_u32*)g, (las_u32*)l, 16, 0, 0);
}

// ---------------- k_wt: net_w[co][ci][3][3] f32 -> wt[tap][cb][co][cl32] bf16
__global__ __launch_bounds__(256) void k_wt(const float* __restrict__ netw, u16* __restrict__ wt) {
    int id = blockIdx.x * 256 + threadIdx.x;
    int cl = id & 31, co = (id >> 5) & 255, cb = (id >> 13) & 7, tap = id >> 16;
    int ci = cb * 32 + cl;
    wt[id] = f2b(netw[((size_t)co * 256 + ci) * 9 + tap]);
}

// ---------------- k_pool0: spatial mean of x -> px[nt][c]
__global__ __launch_bounds__(256) void k_pool0(const float* __restrict__ x, float* __restrict__ px) {
    const int nt = blockIdx.x, cg = blockIdx.y;
    const int wv = threadIdx.x >> 6, ln = threadIdx.x & 63;
    for (int i = 0; i < 16; ++i) {
        int c = cg * 64 + wv * 16 + i;
        const float4* xp = (const float4*)(x + (size_t)nt * PLANE + (size_t)c * HW);
        float s = 0.f;
        for (int k = ln; k < 196; k += 64) { float4 v = xp[k]; s += v.x + v.y + v.z + v.w; }
        #pragma unroll
        for (int o = 32; o; o >>= 1) s += __shfl_xor(s, o);
        if (ln == 0) px[nt * 256 + c] = s * (1.f / 784.f);
    }
}

// ---------------- k_zero: zero the border pixels of each padded image
__global__ __launch_bounds__(256) void k_zero(u16* __restrict__ xstg) {
    const int nt = blockIdx.x, tid = threadIdx.x;
    for (int it = 0; it < 15; ++it) {
        int cid = it * 256 + tid;
        if (cid < 3712) {
            int pxi = cid >> 5, ch = cid & 31;
            int pidx;
            if (pxi < 30) pidx = pxi;
            else if (pxi < 60) pidx = 29 * 30 + (pxi - 30);
            else { int k = pxi - 60; pidx = (1 + (k >> 1)) * 30 + (k & 1) * 29; }
            *(u16x8*)(xstg + ((size_t)nt * PADPX + pidx) * 256 + ch * 8) = (u16x8){0,0,0,0,0,0,0,0};
        }
    }
}

// ---------------- k_se0: temporal 3-tap shift of pooled values (shift∘pool == pool∘shift)
__global__ __launch_bounds__(256) void k_se0(const float* __restrict__ px,
                                             const float* __restrict__ taw,
                                             float* __restrict__ ps) {
    int b = blockIdx.x, c = threadIdx.x;
    float w0 = taw[c * 3], w1 = taw[c * 3 + 1], w2 = taw[c * 3 + 2];
    float pr[8];
    #pragma unroll
    for (int t = 0; t < 8; ++t) pr[t] = px[(b * 8 + t) * 256 + c];
    #pragma unroll
    for (int t = 0; t < 8; ++t) {
        float v = w1 * pr[t];
        if (t > 0) v += w0 * pr[t - 1];
        if (t < 7) v += w2 * pr[t + 1];
        ps[(b * 8 + t) * 256 + c] = v;
    }
}

// ---------------- k_se: SE chain -> gl = 1 + sigmoid
__global__ __launch_bounds__(256) void k_se(const float* __restrict__ ps,
                                            const float* __restrict__ wse,
                                            const float* __restrict__ gamma,
                                            const float* __restrict__ beta,
                                            const float* __restrict__ w1,
                                            float* __restrict__ gl) {
    __shared__ float y3_l[2048];
    __shared__ float sc_l[16], bi_l[16];
    const int tid = threadIdx.x;
    const int b = tid >> 4, o = tid & 15;
    float acc[8] = {0, 0, 0, 0, 0, 0, 0, 0};
    const float* psb = ps + b * 2048;        // row-major [NT,C] viewed flat as [B][C][T]
    for (int c2 = 0; c2 < 256; ++c2) {
        float pv[8];
        #pragma unroll
        for (int i = 0; i < 8; ++i) pv[i] = psb[c2 * 8 + i];
        float ww0 = wse[(o * 256 + c2) * 3];
        float ww1 = wse[(o * 256 + c2) * 3 + 1];
        float ww2 = wse[(o * 256 + c2) * 3 + 2];
        #pragma unroll
        for (int t = 0; t < 8; ++t) {
            float v = ww1 * pv[t];
            if (t > 0) v += ww0 * pv[t - 1];
            if (t < 7) v += ww2 * pv[t + 1];
            acc[t] += v;
        }
    }
    #pragma unroll
    for (int t = 0; t < 8; ++t) y3_l[b * 128 + o * 8 + t] = acc[t];
    __syncthreads();
    if (tid < 16) {
        float s = 0.f, sq = 0.f;
        for (int i = 0; i < 128; ++i) {
            float v = y3_l[(i >> 3) * 128 + tid * 8 + (i & 7)];
            s += v; sq += v * v;
        }
        float m = s * (1.f / 128.f);
        float var = sq * (1.f / 128.f) - m * m;
        float rs = rsqrtf(var + 1e-5f) * gamma[tid];
        sc_l[tid] = rs;
        bi_l[tid] = beta[tid] - m * rs;
    }
    __syncthreads();
    #pragma unroll
    for (int t = 0; t < 8; ++t)
        y3_l[b * 128 + o * 8 + t] = fmaxf(acc[t] * sc_l[o] + bi_l[o], 0.f);
    __syncthreads();
    for (int k = 0; k < 128; ++k) {
        int id = tid + 256 * k;            // flat [B][256][T] == flat [NT][C]
        int bb = id >> 11, o2 = (id >> 3) & 255, t = id & 7;
        float a = 0.f;
        #pragma unroll
        for (int oo = 0; oo < 16; ++oo) a += w1[o2 * 16 + oo] * y3_l[bb * 128 + oo * 8 + t];
        gl[id] = 1.f + 1.f / (1.f + __expf(-a));
    }
}

// ---------------- k_fused: temporal shift + gate + transpose -> xstg[nt][padpix][c] bf16
__global__ __launch_bounds__(256) void k_fused(const float* __restrict__ x,
                                               const float* __restrict__ taw,
                                               const float* __restrict__ gl,
                                               u16* __restrict__ xstg) {
    const int pt = blockIdx.x;      // 0..13 (56-pixel strips = 2 rows)
    const int nt = blockIdx.y;
    const int tid = threadIdx.x, wv = tid >> 6, ln = tid & 63;
    const int p0 = pt * 56;
    const int tseg = nt & 7;
    __shared__ float taw_l[768];
    __shared__ float gl_l[256];
    __shared__ __align__(16) u16 xs_l[256 * 57];
    for (int i = tid; i < 768; i += 256) taw_l[i] = taw[i];
    gl_l[tid] = gl[nt * 256 + tid];
    __syncthreads();
    const int p = ln;
    const bool act = p < 56;
    for (int j = 0; j < 64; ++j) {
        const int c = j * 4 + wv;
        const int base = c * HW + p0 + p;
        const float w0 = taw_l[c * 3], w1 = taw_l[c * 3 + 1], w2 = taw_l[c * 3 + 2];
        float vm = 0.f, v0 = 0.f, vp = 0.f;
        if (act) {
            v0 = x[(size_t)nt * PLANE + base];
            // skip neighbor-plane loads when the tap weight is exactly 0 (wave-uniform)
            if (w0 != 0.f && tseg > 0) vm = x[(size_t)(nt - 1) * PLANE + base];
            if (w2 != 0.f && tseg < 7) vp = x[(size_t)(nt + 1) * PLANE + base];
        }
        float xs = (w0 * vm + w1 * v0 + w2 * vp) * gl_l[c];
        if (act) xs_l[c * 57 + p] = f2b(xs);
    }
    __syncthreads();
    for (int k = 0; k < 7; ++k) {
        int id = k * 256 + tid;        // 0..1791
        int pp = id >> 5;              // 0..55
        int c0 = (id & 31) * 8;
        u16x8 v;
        #pragma unroll
        for (int i = 0; i < 8; ++i) v[i] = xs_l[(c0 + i) * 57 + pp];
        int gp = p0 + pp;
        int r = gp / 28, cc = gp % 28;
        int pidx = (r + 1) * 30 + (cc + 1);
        *(u16x8*)(xstg + ((size_t)nt * PADPX + pidx) * 256 + c0) = v;
    }
}

// ---------------- k_conv: 3x3 conv; wave=32co x 112px; A software-pipelined by one tap
__global__ __launch_bounds__(256, 3) void k_conv(const u16* __restrict__ xstg,
                                                 const u16* __restrict__ wt,
                                                 const float* __restrict__ netb,
                                                 float* __restrict__ out) {
    const int pt = blockIdx.x;   // 0..6 : 4 output rows (112 px)
    const int mt = blockIdx.y;   // 0..1 : 128 c_out half
    const int nt = blockIdx.z;   // 0..127
    const int tid = threadIdx.x, wv = tid >> 6, ln = tid & 63;
    __shared__ __align__(16) u16 z_l[2][6144];   // [pix 192][ch 32], 12KB each
    const int g8 = (ln >> 4) * 8;
    const int p = ln & 15;
    int pb[7];
    #pragma unroll
    for (int nf = 0; nf < 7; ++nf) {
        int n = nf * 16 + p;
        pb[nf] = (n / 28) * 30 + (n % 28);     // padded base pos
    }
    f32x4 acc[2][7];
    #pragma unroll
    for (int a = 0; a < 2; ++a)
        #pragma unroll
        for (int b = 0; b < 7; ++b) acc[a][b] = (f32x4){0.f, 0.f, 0.f, 0.f};

    const size_t gbase = ((size_t)nt * PADPX + pt * 120) * 256;   // u16 units

    auto stage = [&](int cb, int buf) {
        #pragma unroll
        for (int s = 0; s < 3; ++s) {
            int k = wv * 3 + s;
            int chunk = k * 64 + ln;
            int pix = chunk >> 2, q = chunk & 3;
            const u16* g = xstg + gbase + (size_t)pix * 256 + cb * 32 + q * 8;
            gload16(g, &z_l[buf][k * 512]);
        }
    };
    auto aload = [&](int tap, int cb, bf16x8* af) {
        const u16* ab = wt + (((size_t)tap * 8 + cb) * 256 + mt * 128 + wv * 32) * 32;
        af[0] = *(const bf16x8*)(ab + p * 32 + g8);
        af[1] = *(const bf16x8*)(ab + (16 + p) * 32 + g8);
    };

    bf16x8 afc[2], afn[2];
    aload(0, 0, afc);
    stage(0, 0);
    for (int cb = 0; cb < 8; ++cb) {
        __syncthreads();                       // buf[cb&1] ready (vmcnt(0) drain)
        if (cb < 7) stage(cb + 1, (cb + 1) & 1);
        const u16* zl = z_l[cb & 1];
        #pragma unroll
        for (int tap = 0; tap < 9; ++tap) {
            if (tap < 8) aload(tap + 1, cb, afn);
            else if (cb < 7) aload(0, cb + 1, afn);
            const int po = (tap / 3) * 30 + (tap % 3);
            #pragma unroll
            for (int nf = 0; nf < 7; ++nf) {
                bf16x8 bf = *(const bf16x8*)&zl[(pb[nf] + po) * 32 + g8];
                acc[0][nf] = __builtin_amdgcn_mfma_f32_16x16x32_bf16(afc[0], bf, acc[0][nf], 0, 0, 0);
                acc[1][nf] = __builtin_amdgcn_mfma_f32_16x16x32_bf16(afc[1], bf, acc[1][nf], 0, 0, 0);
            }
            afc[0] = afn[0]; afc[1] = afn[1];
        }
    }
    // epilogue: D layout col=lane&15, row=(lane>>4)*4+i
    const int colp = ln & 15, rowp = (ln >> 4) * 4;
    const int o0 = pt * 112;
    #pragma unroll
    for (int mf = 0; mf < 2; ++mf) {
        #pragma unroll
        for (int i = 0; i < 4; ++i) {
            int co = mt * 128 + wv * 32 + mf * 16 + rowp + i;
            float bias = netb[co];
            float* ob = out + ((size_t)nt * 256 + co) * HW + o0;
            #pragma unroll
            for (int nf = 0; nf < 7; ++nf)
                ob[nf * 16 + colp] = acc[mf][nf][i] + bias;
        }
    }
}

extern "C" void kernel_launch(void* const* d_in, const int* in_sizes, int n_in,
                              void* d_out, int out_size, void* d_ws, size_t ws_size,
                              hipStream_t stream) {
    const float* x     = (const float*)d_in[0];
    const float* taw   = (const float*)d_in[1];
    const float* wse   = (const float*)d_in[2];
    const float* gamma = (const float*)d_in[3];
    const float* beta  = (const float*)d_in[4];
    const float* w1    = (const float*)d_in[5];
    const float* netw  = (const float*)d_in[6];
    const float* netb  = (const float*)d_in[7];
    float* out = (float*)d_out;
    char* ws = (char*)d_ws;
    float* px   = (float*)(ws + OFF_PX);
    float* ps   = (float*)(ws + OFF_PS);
    float* gl   = (float*)(ws + OFF_GL);
    u16*   wt   = (u16*)(ws + OFF_WT);
    u16*   xstg = (u16*)(ws + OFF_XSTG);

    k_wt<<<dim3(2304), dim3(256), 0, stream>>>(netw, wt);
    k_zero<<<dim3(128), dim3(256), 0, stream>>>(xstg);
    k_pool0<<<dim3(128, 4), dim3(256), 0, stream>>>(x, px);
    k_se0<<<dim3(16), dim3(256), 0, stream>>>(px, taw, ps);
    k_se<<<dim3(1), dim3(256), 0, stream>>>(ps, wse, gamma, beta, w1, gl);
    k_fused<<<dim3(14, 128), dim3(256), 0, stream>>>(x, taw, gl, xstg);
    k_conv<<<dim3(7, 2, 128), dim3(256), 0, stream>>>(xstg, wt, netb, out);
}